// Round 1
// 785.361 us; speedup vs baseline: 1.6851x; 1.6851x over previous
//
#include <hip/hip_runtime.h>

typedef unsigned short u16;
typedef unsigned int u32;
typedef __bf16 bf16x8 __attribute__((ext_vector_type(8)));
typedef float f32x4 __attribute__((ext_vector_type(4)));

#define NPAPER 100000
#define NAUTH  50000
#define PHALF  50000
#define KP 40   // LDS row stride (elems): 80B, 16B-aligned rows -> conflict-free b128

struct alignas(16) U4 { u32 a, b, c, d; };
struct alignas(16) F4 { float x, y, z, w; };

__device__ __forceinline__ float bf2f(u16 u) {
    union { u32 i; float f; } v; v.i = ((u32)u) << 16; return v.f;
}
__device__ __forceinline__ u16 f2bf(float f) {
    union { float f; u32 i; } v; v.f = f;
    u32 u = v.i;
    return (u16)((u + 0x7FFFu + ((u >> 16) & 1u)) >> 16);
}

// flags: [0]=idx_is_int64 [1]=x_is_f32 [2]=W_is_f32 [3]=b_is_f32 [4]=0 const (bf16)
__device__ __forceinline__ float ldf(const void* p, size_t i, int f32) {
    return f32 ? ((const float*)p)[i] : bf2f(((const u16*)p)[i]);
}

__global__ void detect_dtypes(const int* __restrict__ e, const u32* __restrict__ x,
                              const u32* __restrict__ w, const u32* __restrict__ bb,
                              int* __restrict__ flags)
{
    int t = threadIdx.x, wave = t >> 6, lane = t & 63;
    if (wave == 0) {
        int v = e[lane];
        unsigned long long m = __ballot((lane & 1) && v == 0);
        if (lane == 0) { flags[0] = (__popcll(m) >= 24) ? 1 : 0; flags[4] = 0; }
    } else {
        const u32* p = (wave == 1) ? x : ((wave == 2) ? w : bb);
        u32 wd = p[lane];
        int ex = (int)((wd >> 7) & 0xFFu);   // exponent of low-half-as-bf16
        unsigned long long m = __ballot(ex >= 105 && ex <= 140);
        if (lane == 0) flags[wave] = (__popcll(m) >= 40) ? 0 : 1;   // 1 = f32
    }
}

// ---- weight prep (one layer): WTpa[n*256+k] = [Wm0 ; Wr0+Wr1](k,n)
//      WTpb[n*128+k] = Wm1(k,n);  WTa[n*256+k] = [Wm2 ; Wr2](k,n)
__global__ __launch_bounds__(256) void prep_weights(
    const void* __restrict__ Wm, const void* __restrict__ b, const void* __restrict__ Wr,
    u16* __restrict__ WTpa, u16* __restrict__ WTpb, u16* __restrict__ WTa,
    float* __restrict__ biasp, float* __restrict__ biasa,
    const int* __restrict__ flags)
{
    int wf = flags[2], bf = flags[3];
    int tid = blockIdx.x * 256 + threadIdx.x;
    if (tid < 32768) {
        int n = tid >> 8, k = tid & 255;
        float v = (k < 128) ? ldf(Wm, k * 128 + n, wf)
                            : ldf(Wr, (k - 128) * 128 + n, wf)
                            + ldf(Wr, 16384 + (k - 128) * 128 + n, wf);
        WTpa[n * 256 + k] = f2bf(v);
    } else if (tid < 49152) {
        int idx = tid - 32768;
        int n = idx >> 7, k = idx & 127;
        WTpb[n * 128 + k] = f2bf(ldf(Wm, 16384 + k * 128 + n, wf));
    } else if (tid < 81920) {
        int idx = tid - 49152;
        int n = idx >> 8, k = idx & 255;
        float v = (k < 128) ? ldf(Wm, 2 * 16384 + k * 128 + n, wf)
                            : ldf(Wr, 2 * 16384 + (k - 128) * 128 + n, wf);
        WTa[n * 256 + k] = f2bf(v);
    } else if (tid < 82176) {
        int i = tid - 81920;
        if (i < 128) biasp[i] = ldf(b, i, bf) + ldf(b, 128 + i, bf);
        else         biasa[i - 128] = ldf(b, 256 + (i - 128), bf);
    }
}

// ---------------- CSR build ----------------
__global__ __launch_bounds__(256) void hist_kernel(
    const int* __restrict__ dst, int E, int* __restrict__ cnt,
    const int* __restrict__ flags)
{
    int i = blockIdx.x * 256 + threadIdx.x;
    if (i >= E) return;
    int d = dst[flags[0] ? 2 * i : i];
    atomicAdd(&cnt[d], 1);
}

// ---- hierarchical exclusive scan: blksum -> partials scan -> write ----
// pass 1: each block reduces its 1024-element chunk -> partials[blockIdx]
__global__ __launch_bounds__(256) void scan_blksum(
    const int* __restrict__ cnt, int N, int* __restrict__ partials)
{
    __shared__ int ws[4];
    int t = threadIdx.x, lane = t & 63, wave = t >> 6;
    int i0 = blockIdx.x * 1024 + t * 4;
    int s = 0;
    #pragma unroll
    for (int j = 0; j < 4; ++j) {
        int i = i0 + j;
        if (i < N) s += cnt[i];
    }
    #pragma unroll
    for (int off = 32; off; off >>= 1) s += __shfl_xor(s, off);
    if (lane == 0) ws[wave] = s;
    __syncthreads();
    if (t == 0) partials[blockIdx.x] = ws[0] + ws[1] + ws[2] + ws[3];
}

// pass 2: single block exclusive-scans <=128 partials in place
__global__ __launch_bounds__(128) void scan_partials(int* __restrict__ partials, int nb)
{
    __shared__ int bs[128];
    int t = threadIdx.x;
    int v = (t < nb) ? partials[t] : 0;
    bs[t] = v;
    __syncthreads();
    for (int off = 1; off < 128; off <<= 1) {
        int u = (t >= off) ? bs[t - off] : 0;
        __syncthreads();
        bs[t] += u;
        __syncthreads();
    }
    if (t < nb) partials[t] = (t == 0) ? 0 : bs[t - 1];
}

// pass 3: in-block exclusive scan + block offset -> rowptr/cursor
__global__ __launch_bounds__(256) void scan_write(
    const int* __restrict__ cnt, int N, const int* __restrict__ partials,
    int* __restrict__ rowptr, int* __restrict__ cursor)
{
    __shared__ int ws[4];
    int t = threadIdx.x, lane = t & 63, wave = t >> 6;
    int i0 = blockIdx.x * 1024 + t * 4;
    int v[4];
    #pragma unroll
    for (int j = 0; j < 4; ++j) {
        int i = i0 + j;
        v[j] = (i < N) ? cnt[i] : 0;
    }
    int s = v[0] + v[1] + v[2] + v[3];
    int sc = s;
    #pragma unroll
    for (int off = 1; off < 64; off <<= 1) {
        int u = __shfl_up(sc, off);
        if (lane >= off) sc += u;
    }
    if (lane == 63) ws[wave] = sc;
    __syncthreads();
    int woff = 0;
    #pragma unroll
    for (int wv = 0; wv < 3; ++wv) if (wv < wave) woff += ws[wv];
    int run = partials[blockIdx.x] + woff + (sc - s);
    #pragma unroll
    for (int j = 0; j < 4; ++j) {
        int i = i0 + j;
        if (i < N) {
            rowptr[i] = run; cursor[i] = run;
            run += v[j];
            if (i == N - 1) rowptr[N] = run;
        }
    }
}

__global__ __launch_bounds__(256) void scatter_kernel(
    const int* __restrict__ src, const int* __restrict__ dst, int E,
    int* __restrict__ cursor, int* __restrict__ srt,
    const int* __restrict__ flags)
{
    int i = blockIdx.x * 256 + threadIdx.x;
    if (i >= E) return;
    int ii = flags[0] ? 2 * i : i;
    int d = dst[ii];
    int pos = atomicAdd(&cursor[d], 1);
    srt[pos] = src[ii];
}

// ---- CSR gather-mean: one wave per dst row, writes bf16 mean row ----
__global__ __launch_bounds__(256) void agg_csr(
    const void* __restrict__ x, const int* __restrict__ rowptr,
    const int* __restrict__ srt, int lo, int hi,
    u16* __restrict__ M, const int* __restrict__ flags, int xslot)
{
    int r = (blockIdx.x * 256 + threadIdx.x) >> 6;
    int lane = threadIdx.x & 63;
    int d = lo + r;
    if (d >= hi) return;
    int xf32 = flags[xslot];               // wave-uniform
    int e0 = rowptr[d], e1 = rowptr[d + 1];
    float a0 = 0.0f, a1 = 0.0f;
    if (xf32) {
        for (int e = e0; e < e1; ++e) {
            int s = srt[e];
            float2 v = ((const float2*)((const float*)x + (size_t)s * 128))[lane];
            a0 += v.x; a1 += v.y;
        }
    } else {
        for (int e = e0; e < e1; ++e) {
            int s = srt[e];
            u32 pk = ((const u32*)((const u16*)x + (size_t)s * 128))[lane];
            a0 += bf2f((u16)(pk & 0xFFFFu));
            a1 += bf2f((u16)(pk >> 16));
        }
    }
    float rcp = 1.0f / fmaxf((float)(e1 - e0), 1.0f);
    u32 pk = (u32)f2bf(a0 * rcp) | ((u32)f2bf(a1 * rcp) << 16);
    ((u32*)(M + (size_t)r * 128))[lane] = pk;
}

// ---- fused GEMM/bias/accum/relu over rows [rowbase, Mhi) ----
// K=256: [mean | root] @ WT^T ; K=128: [mean] @ WT^T. WT is [128][K] = B^T.
// Mean rows are bf16 in M (row 0 = global row `rowbase`).
__global__ __launch_bounds__(256) void gemm_kernel(
    const u16* __restrict__ M, int rowbase, int Mhi,
    const void* __restrict__ xroot, const u16* __restrict__ WT,
    const float* __restrict__ bias, void* __restrict__ out, int out_f32,
    int K, int accum, int relu, const int* __restrict__ flags, int rslot)
{
    __shared__ __align__(16) u16 Asm[128 * KP];
    __shared__ __align__(16) u16 Bsm[128 * KP];

    int root_f32 = flags[rslot];

    int t = threadIdx.x;
    int row = t >> 1, kh = t & 1;            // staging: 2 threads/row, 16 elems each
    int grow0 = rowbase + blockIdx.x * 128;
    int grow = grow0 + row;
    int growc = grow < Mhi ? grow : (Mhi - 1);   // clamp loads; stores guarded

    int wave = t >> 6, lane = t & 63;
    int wm = wave >> 1, wn = wave & 1;       // 2x2 wave grid, 64x64 per wave
    int fr = lane & 15, fq = lane >> 4;

    f32x4 acc[4][4] = {};

    int ksteps = K >> 5;
    for (int ks = 0; ks < ksteps; ++ks) {
        int koff = ks * 32 + kh * 16;
        int chunk = koff >> 7;               // 0 = mean, 1 = root (K==256 only)
        int kin = koff & 127;

        alignas(16) u16 av[16];
        alignas(16) u16 bv[16];

        if (chunk == 0) {
            const U4* mp = (const U4*)(M + (size_t)(growc - rowbase) * 128 + kin);
            ((U4*)av)[0] = mp[0];
            ((U4*)av)[1] = mp[1];
        } else if (root_f32) {
            const F4* xpq = (const F4*)((const float*)xroot + (size_t)growc * 128 + kin);
            #pragma unroll
            for (int i = 0; i < 4; ++i) {
                F4 f = xpq[i];
                av[i * 4 + 0] = f2bf(f.x);
                av[i * 4 + 1] = f2bf(f.y);
                av[i * 4 + 2] = f2bf(f.z);
                av[i * 4 + 3] = f2bf(f.w);
            }
        } else {
            const U4* xpq = (const U4*)((const u16*)xroot + (size_t)growc * 128 + kin);
            ((U4*)av)[0] = xpq[0];
            ((U4*)av)[1] = xpq[1];
        }
        {
            const U4* wp = (const U4*)(WT + (size_t)row * K + koff);
            ((U4*)bv)[0] = wp[0];
            ((U4*)bv)[1] = wp[1];
        }

        __syncthreads();   // prior iteration's frag reads complete
        {
            u16* ad = Asm + row * KP + kh * 16;
            u16* bd = Bsm + row * KP + kh * 16;
            ((U4*)ad)[0] = ((const U4*)av)[0];
            ((U4*)ad)[1] = ((const U4*)av)[1];
            ((U4*)bd)[0] = ((const U4*)bv)[0];
            ((U4*)bd)[1] = ((const U4*)bv)[1];
        }
        __syncthreads();

        const u16* Ab = Asm + (wm * 64 + fr) * KP + fq * 8;
        const u16* Bb = Bsm + (wn * 64 + fr) * KP + fq * 8;
        bf16x8 af[4], bfv[4];
        #pragma unroll
        for (int r = 0; r < 4; ++r) af[r] = *(const bf16x8*)(Ab + r * 16 * KP);
        #pragma unroll
        for (int c = 0; c < 4; ++c) bfv[c] = *(const bf16x8*)(Bb + c * 16 * KP);
        #pragma unroll
        for (int r = 0; r < 4; ++r)
            #pragma unroll
            for (int c = 0; c < 4; ++c)
                acc[r][c] = __builtin_amdgcn_mfma_f32_16x16x32_bf16(af[r], bfv[c], acc[r][c], 0, 0, 0);
    }

    // epilogue: C/D layout col=lane&15, row=(lane>>4)*4+reg (m89-verified)
    #pragma unroll
    for (int r = 0; r < 4; ++r) {
        int orow0 = grow0 + wm * 64 + r * 16 + fq * 4;
        #pragma unroll
        for (int c = 0; c < 4; ++c) {
            int col = wn * 64 + c * 16 + fr;
            float bvl = bias ? bias[col] : 0.0f;
            #pragma unroll
            for (int g = 0; g < 4; ++g) {
                int orow = orow0 + g;
                if (orow < Mhi) {
                    size_t oi = (size_t)orow * 128 + col;
                    float v = acc[r][c][g] + bvl;
                    if (accum)
                        v += out_f32 ? ((float*)out)[oi] : bf2f(((u16*)out)[oi]);
                    if (relu) v = fmaxf(v, 0.0f);
                    if (out_f32) ((float*)out)[oi] = v;
                    else         ((u16*)out)[oi] = f2bf(v);
                }
            }
        }
    }
}

extern "C" void kernel_launch(void* const* d_in, const int* in_sizes, int n_in,
                              void* d_out, int out_size, void* d_ws, size_t ws_size,
                              hipStream_t stream)
{
    const void* xp  = d_in[0];
    const void* xa  = d_in[1];
    const void* Wm1 = d_in[2];
    const void* b1  = d_in[3];
    const void* Wr1 = d_in[4];
    const void* Wm2 = d_in[5];
    const void* b2  = d_in[6];
    const void* Wr2 = d_in[7];
    const int* e0s = (const int*)d_in[8];
    const int* e0d = (const int*)d_in[9];
    const int* e1s = (const int*)d_in[10];
    const int* e1d = (const int*)d_in[11];
    const int* e2s = (const int*)d_in[12];
    const int* e2d = (const int*)d_in[13];
    int E0 = in_sizes[8], E1 = in_sizes[10], E2 = in_sizes[12];

    // ---- ws layout, ~53 MiB total ----
    char* w = (char*)d_ws;
    int*   flags  = (int*)w;                          // 5 ints
    float* biasp1 = (float*)(w + 256);
    float* biasa1 = biasp1 + 128;
    float* biasp2 = biasa1 + 128;
    float* biasa2 = biasp2 + 128;
    u16*   WTp1a  = (u16*)(w + 2304);                 // 128x256
    u16*   WTp1b  = WTp1a + 32768;                    // 128x128
    u16*   WTa1   = WTp1b + 16384;                    // 128x256
    u16*   WTp2a  = WTa1  + 32768;
    u16*   WTp2b  = WTp2a + 32768;
    u16*   WTa2   = WTp2b + 16384;
    int*   rp0    = (int*)(WTa2 + 32768);             // 100001
    int*   rp1    = rp0 + (NPAPER + 1);               // 100001
    int*   rp2    = rp1 + (NPAPER + 1);               // 50001
    int*   cnt    = rp2 + (NAUTH + 1);                // 100000 (shared temp)
    int*   cursor = cnt + NPAPER;                     // 100000 (shared temp)
    int*   srt0   = cursor + NPAPER;                  // 300000
    int*   srt1   = srt0 + 300000;                    // 150000
    int*   srt2   = srt1 + 150000;                    // 150000
    u16*   hpw    = (u16*)(srt2 + 150000);            // 100000x128 bf16
    u16*   haw    = hpw + (size_t)NPAPER * 128;       // 50000x128 bf16
    u16*   Mbuf   = haw + (size_t)NAUTH * 128;        // 50000x128 bf16 mean scratch
    int*   partials = (int*)(Mbuf + (size_t)NAUTH * 128);  // 128 ints scan temp

    float* outp = (float*)d_out;                      // final output f32
    float* outa = outp + (size_t)NPAPER * 128;

    detect_dtypes<<<1, 256, 0, stream>>>(e0s, (const u32*)xp, (const u32*)Wm1,
                                         (const u32*)b1, flags);
    prep_weights<<<321, 256, 0, stream>>>(Wm1, b1, Wr1, WTp1a, WTp1b, WTa1,
                                          biasp1, biasa1, flags);
    prep_weights<<<321, 256, 0, stream>>>(Wm2, b2, Wr2, WTp2a, WTp2b, WTa2,
                                          biasp2, biasa2, flags);

    // ---- CSR build (3 edge types, sequential reuse of cnt/cursor) ----
    {
        const int* ss[3] = { e0s, e1s, e2s };
        const int* dd[3] = { e0d, e1d, e2d };
        int        EE[3] = { E0, E1, E2 };
        int        NN[3] = { NPAPER, NPAPER, NAUTH };
        int*       rp[3] = { rp0, rp1, rp2 };
        int*       st[3] = { srt0, srt1, srt2 };
        for (int ty = 0; ty < 3; ++ty) {
            hipMemsetAsync(cnt, 0, (size_t)NN[ty] * 4, stream);
            hist_kernel<<<(EE[ty] + 255) / 256, 256, 0, stream>>>(dd[ty], EE[ty], cnt, flags);
            int nb = (NN[ty] + 1023) / 1024;
            scan_blksum<<<nb, 256, 0, stream>>>(cnt, NN[ty], partials);
            scan_partials<<<1, 128, 0, stream>>>(partials, nb);
            scan_write<<<nb, 256, 0, stream>>>(cnt, NN[ty], partials, rp[ty], cursor);
            scatter_kernel<<<(EE[ty] + 255) / 256, 256, 0, stream>>>(
                ss[ty], dd[ty], EE[ty], cursor, st[ty], flags);
        }
    }

    for (int layer = 0; layer < 2; ++layer) {
        const void* fp = layer ? (const void*)hpw : xp;
        const void* fa = layer ? (const void*)haw : xa;
        void* op = layer ? (void*)outp : (void*)hpw;
        void* oa = layer ? (void*)outa : (void*)haw;
        int of32 = layer ? 1 : 0;
        u16* WTpa = layer ? WTp2a : WTp1a;
        u16* WTpb = layer ? WTp2b : WTp1b;
        u16* WTau = layer ? WTa2  : WTa1;
        float* bp = layer ? biasp2 : biasp1;
        float* ba = layer ? biasa2 : biasa1;
        int slot = layer ? 4 : 1;            // feature dtype: flags[1] / bf16-const
        int relu = layer ? 0 : 1;

        // papers pass 1: op = mean_cites @ Wm0 + fp @ (Wr0+Wr1) + (b0+b1)
        for (int h = 0; h < 2; ++h) {
            int lo = h * PHALF, hi = lo + PHALF;
            agg_csr<<<(PHALF + 3) / 4, 256, 0, stream>>>(fp, rp0, srt0, lo, hi, Mbuf, flags, slot);
            gemm_kernel<<<(PHALF + 127) / 128, 256, 0, stream>>>(
                Mbuf, lo, hi, fp, WTpa, bp, op, of32, 256, 0, 0, flags, slot);
        }
        // papers pass 2: op += mean_writes @ Wm1 ; relu (layer 1)
        for (int h = 0; h < 2; ++h) {
            int lo = h * PHALF, hi = lo + PHALF;
            agg_csr<<<(PHALF + 3) / 4, 256, 0, stream>>>(fa, rp1, srt1, lo, hi, Mbuf, flags, slot);
            gemm_kernel<<<(PHALF + 127) / 128, 256, 0, stream>>>(
                Mbuf, lo, hi, nullptr, WTpb, nullptr, op, of32, 128, 1, relu, flags, slot);
        }
        // authors (single pass, 50000 rows): oa = mean_wb @ Wm2 + fa @ Wr2 + b2
        agg_csr<<<(NAUTH + 3) / 4, 256, 0, stream>>>(fp, rp2, srt2, 0, NAUTH, Mbuf, flags, slot);
        gemm_kernel<<<(NAUTH + 127) / 128, 256, 0, stream>>>(
            Mbuf, 0, NAUTH, fa, WTau, ba, oa, of32, 256, 0, relu, flags, slot);
    }
}

// Round 2
// 641.349 us; speedup vs baseline: 2.0635x; 1.2245x over previous
//
#include <hip/hip_runtime.h>

typedef unsigned short u16;
typedef unsigned int u32;
typedef __bf16 bf16x8 __attribute__((ext_vector_type(8)));
typedef float f32x4 __attribute__((ext_vector_type(4)));

#define NPAPER 100000
#define NAUTH  50000
#define KP 40   // LDS row stride (elems): 80B, 16B-aligned rows -> conflict-free b128

struct alignas(16) U4 { u32 a, b, c, d; };
struct alignas(16) F4 { float x, y, z, w; };

__device__ __forceinline__ float bf2f(u16 u) {
    union { u32 i; float f; } v; v.i = ((u32)u) << 16; return v.f;
}
__device__ __forceinline__ u16 f2bf(float f) {
    union { float f; u32 i; } v; v.f = f;
    u32 u = v.i;
    return (u16)((u + 0x7FFFu + ((u >> 16) & 1u)) >> 16);
}

// flags: [0]=idx_is_int64 [1]=x_is_f32 [2]=W_is_f32 [3]=b_is_f32
__device__ __forceinline__ float ldf(const void* p, size_t i, int f32) {
    return f32 ? ((const float*)p)[i] : bf2f(((const u16*)p)[i]);
}

__global__ void detect_dtypes(const int* __restrict__ e, const u32* __restrict__ x,
                              const u32* __restrict__ w, const u32* __restrict__ bb,
                              int* __restrict__ flags)
{
    int t = threadIdx.x, wave = t >> 6, lane = t & 63;
    if (wave == 0) {
        int v = e[lane];
        unsigned long long m = __ballot((lane & 1) && v == 0);
        if (lane == 0) flags[0] = (__popcll(m) >= 24) ? 1 : 0;
    } else {
        const u32* p = (wave == 1) ? x : ((wave == 2) ? w : bb);
        u32 wd = p[lane];
        int ex = (int)((wd >> 7) & 0xFFu);   // exponent of low-half-as-bf16
        unsigned long long m = __ballot(ex >= 105 && ex <= 140);
        if (lane == 0) flags[wave] = (__popcll(m) >= 40) ? 0 : 1;   // 1 = f32
    }
}

// ---- upfront feature conversion: x_paper,x_author -> bf16 (copy if already bf16)
__global__ __launch_bounds__(256) void convert_x(
    const void* __restrict__ xp, const void* __restrict__ xa,
    u16* __restrict__ xpb, u16* __restrict__ xab, const int* __restrict__ flags)
{
    int f32 = flags[1];
    size_t i = ((size_t)blockIdx.x * 256 + threadIdx.x) * 8;
    const size_t np = (size_t)NPAPER * 128, ntot = np + (size_t)NAUTH * 128;
    if (i >= ntot) return;
    const void* s; u16* d; size_t off;
    if (i < np) { s = xp; d = xpb; off = i; }
    else        { s = xa; d = xab; off = i - np; }
    alignas(16) u16 o[8];
    if (f32) {
        const F4* f = (const F4*)((const float*)s + off);
        F4 f0 = f[0], f1 = f[1];
        o[0] = f2bf(f0.x); o[1] = f2bf(f0.y); o[2] = f2bf(f0.z); o[3] = f2bf(f0.w);
        o[4] = f2bf(f1.x); o[5] = f2bf(f1.y); o[6] = f2bf(f1.z); o[7] = f2bf(f1.w);
    } else {
        *(U4*)o = *(const U4*)((const u16*)s + off);
    }
    *(U4*)(d + off) = *(const U4*)o;
}

// ---- weight prep (one layer):
//  WTp[n*384+k]: k<128 -> Wm0(k,n); k<256 -> Wm1(k-128,n); else Wr0+Wr1(k-256,n)
//  WTa[n*256+k]: k<128 -> Wm2(k,n); else Wr2(k-128,n)
//  biasp = b0+b1; biasa = b2
__global__ __launch_bounds__(256) void prep_weights(
    const void* __restrict__ Wm, const void* __restrict__ b, const void* __restrict__ Wr,
    u16* __restrict__ WTp, u16* __restrict__ WTa,
    float* __restrict__ biasp, float* __restrict__ biasa,
    const int* __restrict__ flags)
{
    int wf = flags[2], bf = flags[3];
    int tid = blockIdx.x * 256 + threadIdx.x;
    if (tid < 49152) {
        int n = tid / 384, k = tid - n * 384;
        float v;
        if (k < 128)      v = ldf(Wm, k * 128 + n, wf);
        else if (k < 256) v = ldf(Wm, 16384 + (k - 128) * 128 + n, wf);
        else              v = ldf(Wr, (k - 256) * 128 + n, wf)
                            + ldf(Wr, 16384 + (k - 256) * 128 + n, wf);
        WTp[n * 384 + k] = f2bf(v);
    } else if (tid < 81920) {
        int idx = tid - 49152;
        int n = idx >> 8, k = idx & 255;
        float v = (k < 128) ? ldf(Wm, 2 * 16384 + k * 128 + n, wf)
                            : ldf(Wr, 2 * 16384 + (k - 128) * 128 + n, wf);
        WTa[n * 256 + k] = f2bf(v);
    } else if (tid < 82176) {
        int i = tid - 81920;
        if (i < 128) biasp[i] = ldf(b, i, bf) + ldf(b, 128 + i, bf);
        else         biasa[i - 128] = ldf(b, 256 + (i - 128), bf);
    }
}

// ---------------- CSR build (3 edge types concatenated) ----------------
// cnt_all rows: [0,NPAPER) cites->paper, [NPAPER,2*NPAPER) writes->paper,
//               [2*NPAPER, 2*NPAPER+NAUTH) wb->author.  One global scan gives
//               global positions into one srt_all buffer.
__global__ __launch_bounds__(256) void hist3(
    const int* __restrict__ e0d, const int* __restrict__ e1d, const int* __restrict__ e2d,
    int E0, int E1, int E2, int nb0, int nb1,
    int* __restrict__ cnt, const int* __restrict__ flags)
{
    int b = blockIdx.x;
    const int* dptr; int E, base, i;
    if (b < nb0)            { dptr = e0d; E = E0; base = 0;          i = b * 256 + threadIdx.x; }
    else if (b < nb0 + nb1) { dptr = e1d; E = E1; base = NPAPER;     i = (b - nb0) * 256 + threadIdx.x; }
    else                    { dptr = e2d; E = E2; base = 2 * NPAPER; i = (b - nb0 - nb1) * 256 + threadIdx.x; }
    if (i >= E) return;
    int d = dptr[flags[0] ? 2 * i : i];
    atomicAdd(&cnt[base + d], 1);
}

// pass 1: each block reduces its 1024-element chunk -> partials[blockIdx]
__global__ __launch_bounds__(256) void scan_blksum(
    const int* __restrict__ cnt, int N, int* __restrict__ partials)
{
    __shared__ int ws[4];
    int t = threadIdx.x, lane = t & 63, wave = t >> 6;
    int i0 = blockIdx.x * 1024 + t * 4;
    int s = 0;
    #pragma unroll
    for (int j = 0; j < 4; ++j) {
        int i = i0 + j;
        if (i < N) s += cnt[i];
    }
    #pragma unroll
    for (int off = 32; off; off >>= 1) s += __shfl_xor(s, off);
    if (lane == 0) ws[wave] = s;
    __syncthreads();
    if (t == 0) partials[blockIdx.x] = ws[0] + ws[1] + ws[2] + ws[3];
}

// pass 2: single block exclusive-scans <=256 partials in place
__global__ __launch_bounds__(256) void scan_partials(int* __restrict__ partials, int nb)
{
    __shared__ int bs[256];
    int t = threadIdx.x;
    bs[t] = (t < nb) ? partials[t] : 0;
    __syncthreads();
    for (int off = 1; off < 256; off <<= 1) {
        int u = (t >= off) ? bs[t - off] : 0;
        __syncthreads();
        bs[t] += u;
        __syncthreads();
    }
    if (t < nb) partials[t] = (t == 0) ? 0 : bs[t - 1];
}

// pass 3: in-block exclusive scan + block offset -> rowptr/cursor
__global__ __launch_bounds__(256) void scan_write(
    const int* __restrict__ cnt, int N, const int* __restrict__ partials,
    int* __restrict__ rowptr, int* __restrict__ cursor)
{
    __shared__ int ws[4];
    int t = threadIdx.x, lane = t & 63, wave = t >> 6;
    int i0 = blockIdx.x * 1024 + t * 4;
    int v[4];
    #pragma unroll
    for (int j = 0; j < 4; ++j) {
        int i = i0 + j;
        v[j] = (i < N) ? cnt[i] : 0;
    }
    int s = v[0] + v[1] + v[2] + v[3];
    int sc = s;
    #pragma unroll
    for (int off = 1; off < 64; off <<= 1) {
        int u = __shfl_up(sc, off);
        if (lane >= off) sc += u;
    }
    if (lane == 63) ws[wave] = sc;
    __syncthreads();
    int woff = 0;
    #pragma unroll
    for (int wv = 0; wv < 3; ++wv) if (wv < wave) woff += ws[wv];
    int run = partials[blockIdx.x] + woff + (sc - s);
    #pragma unroll
    for (int j = 0; j < 4; ++j) {
        int i = i0 + j;
        if (i < N) {
            rowptr[i] = run; cursor[i] = run;
            run += v[j];
            if (i == N - 1) rowptr[N] = run;
        }
    }
}

__global__ __launch_bounds__(256) void scatter3(
    const int* __restrict__ e0s, const int* __restrict__ e0d,
    const int* __restrict__ e1s, const int* __restrict__ e1d,
    const int* __restrict__ e2s, const int* __restrict__ e2d,
    int E0, int E1, int E2, int nb0, int nb1,
    int* __restrict__ cursor, int* __restrict__ srt,
    const int* __restrict__ flags)
{
    int b = blockIdx.x;
    const int* sptr; const int* dptr; int E, base, i;
    if (b < nb0)            { sptr = e0s; dptr = e0d; E = E0; base = 0;          i = b * 256 + threadIdx.x; }
    else if (b < nb0 + nb1) { sptr = e1s; dptr = e1d; E = E1; base = NPAPER;     i = (b - nb0) * 256 + threadIdx.x; }
    else                    { sptr = e2s; dptr = e2d; E = E2; base = 2 * NPAPER; i = (b - nb0 - nb1) * 256 + threadIdx.x; }
    if (i >= E) return;
    int ii = flags[0] ? 2 * i : i;
    int d = dptr[ii];
    int pos = atomicAdd(&cursor[base + d], 1);
    srt[pos] = sptr[ii];
}

// ---- CSR gather-mean: one wave per dst row, bf16 in, bf16 mean out ----
// writes M[r*mstride + mcol .. +128)
__global__ __launch_bounds__(256) void agg_csr(
    const u16* __restrict__ x, const int* __restrict__ rowptr,
    const int* __restrict__ srt, int nrows,
    u16* __restrict__ M, int mstride, int mcol)
{
    int r = (blockIdx.x * 256 + threadIdx.x) >> 6;
    int lane = threadIdx.x & 63;
    if (r >= nrows) return;
    int e0 = rowptr[r], e1 = rowptr[r + 1];
    float a0 = 0.0f, a1 = 0.0f;
    for (int e = e0; e < e1; ++e) {
        int s = srt[e];
        u32 pk = ((const u32*)(x + (size_t)s * 128))[lane];
        a0 += bf2f((u16)(pk & 0xFFFFu));
        a1 += bf2f((u16)(pk >> 16));
    }
    float rcp = 1.0f / fmaxf((float)(e1 - e0), 1.0f);
    u32 pk = (u32)f2bf(a0 * rcp) | ((u32)f2bf(a1 * rcp) << 16);
    ((u32*)(M + (size_t)r * mstride + mcol))[lane] = pk;
}

// ---- fused GEMM/bias/relu over rows [0, nrows) ----
// A row = [ M[row][0..Km) | root[row][0..128) ], K = Km + 128 (all bf16).
// WT is [128][K] = B^T.  out = A @ WT^T + bias, optional relu.
__global__ __launch_bounds__(256) void gemm_kernel(
    const u16* __restrict__ M, int Mstride, int Km, const u16* __restrict__ root,
    const u16* __restrict__ WT, const float* __restrict__ bias,
    void* __restrict__ out, int out_f32, int K, int nrows, int relu)
{
    __shared__ __align__(16) u16 Asm[128 * KP];
    __shared__ __align__(16) u16 Bsm[128 * KP];

    int t = threadIdx.x;
    int row = t >> 1, kh = t & 1;            // staging: 2 threads/row, 16 elems each
    int grow0 = blockIdx.x * 128;
    int grow = grow0 + row;
    int growc = grow < nrows ? grow : (nrows - 1);   // clamp loads; stores guarded

    int wave = t >> 6, lane = t & 63;
    int wm = wave >> 1, wn = wave & 1;       // 2x2 wave grid, 64x64 per wave
    int fr = lane & 15, fq = lane >> 4;

    f32x4 acc[4][4] = {};

    int ksteps = K >> 5;
    for (int ks = 0; ks < ksteps; ++ks) {
        int koff = ks * 32 + kh * 16;        // 16-elem chunk, never straddles Km

        alignas(16) u16 av[16];
        alignas(16) u16 bv[16];

        const u16* asrc = (koff < Km)
            ? (M + (size_t)growc * Mstride + koff)
            : (root + (size_t)growc * 128 + (koff - Km));
        ((U4*)av)[0] = ((const U4*)asrc)[0];
        ((U4*)av)[1] = ((const U4*)asrc)[1];
        {
            const U4* wp = (const U4*)(WT + (size_t)row * K + koff);
            ((U4*)bv)[0] = wp[0];
            ((U4*)bv)[1] = wp[1];
        }

        __syncthreads();   // prior iteration's frag reads complete
        {
            u16* ad = Asm + row * KP + kh * 16;
            u16* bd = Bsm + row * KP + kh * 16;
            ((U4*)ad)[0] = ((const U4*)av)[0];
            ((U4*)ad)[1] = ((const U4*)av)[1];
            ((U4*)bd)[0] = ((const U4*)bv)[0];
            ((U4*)bd)[1] = ((const U4*)bv)[1];
        }
        __syncthreads();

        const u16* Ab = Asm + (wm * 64 + fr) * KP + fq * 8;
        const u16* Bb = Bsm + (wn * 64 + fr) * KP + fq * 8;
        bf16x8 af[4], bfv[4];
        #pragma unroll
        for (int r = 0; r < 4; ++r) af[r] = *(const bf16x8*)(Ab + r * 16 * KP);
        #pragma unroll
        for (int c = 0; c < 4; ++c) bfv[c] = *(const bf16x8*)(Bb + c * 16 * KP);
        #pragma unroll
        for (int r = 0; r < 4; ++r)
            #pragma unroll
            for (int c = 0; c < 4; ++c)
                acc[r][c] = __builtin_amdgcn_mfma_f32_16x16x32_bf16(af[r], bfv[c], acc[r][c], 0, 0, 0);
    }

    // epilogue: C/D layout col=lane&15, row=(lane>>4)*4+reg (m89-verified)
    #pragma unroll
    for (int r = 0; r < 4; ++r) {
        int orow0 = grow0 + wm * 64 + r * 16 + fq * 4;
        #pragma unroll
        for (int c = 0; c < 4; ++c) {
            int col = wn * 64 + c * 16 + fr;
            float bvl = bias[col];
            #pragma unroll
            for (int g = 0; g < 4; ++g) {
                int orow = orow0 + g;
                if (orow < nrows) {
                    size_t oi = (size_t)orow * 128 + col;
                    float v = acc[r][c][g] + bvl;
                    if (relu) v = fmaxf(v, 0.0f);
                    if (out_f32) ((float*)out)[oi] = v;
                    else         ((u16*)out)[oi] = f2bf(v);
                }
            }
        }
    }
}

extern "C" void kernel_launch(void* const* d_in, const int* in_sizes, int n_in,
                              void* d_out, int out_size, void* d_ws, size_t ws_size,
                              hipStream_t stream)
{
    const void* xp  = d_in[0];
    const void* xa  = d_in[1];
    const void* Wm1 = d_in[2];
    const void* b1  = d_in[3];
    const void* Wr1 = d_in[4];
    const void* Wm2 = d_in[5];
    const void* b2  = d_in[6];
    const void* Wr2 = d_in[7];
    const int* e0s = (const int*)d_in[8];
    const int* e0d = (const int*)d_in[9];
    const int* e1s = (const int*)d_in[10];
    const int* e1d = (const int*)d_in[11];
    const int* e2s = (const int*)d_in[12];
    const int* e2d = (const int*)d_in[13];
    int E0 = in_sizes[8], E1 = in_sizes[10], E2 = in_sizes[12];

    const int NROWS = 2 * NPAPER + NAUTH;    // 250000 concatenated CSR rows

    // ---- ws layout, ~147 MiB total (ws is ~300 MiB per harness poison fill) ----
    char* w = (char*)d_ws;
    int*   flags  = (int*)w;                          // 5 ints
    float* biasp1 = (float*)(w + 256);
    float* biasa1 = biasp1 + 128;
    float* biasp2 = biasa1 + 128;
    float* biasa2 = biasp2 + 128;
    u16*   WTp1   = (u16*)(w + 2304);                 // 128x384
    u16*   WTa1   = WTp1 + 49152;                     // 128x256
    u16*   WTp2   = WTa1 + 32768;
    u16*   WTa2   = WTp2 + 49152;
    int*   rp_all = (int*)(WTa2 + 32768);             // 250001 (+pad)
    int*   cnt_all  = rp_all + 250004;                // 250000
    int*   cur_all  = cnt_all + 250000;               // 250000
    int*   srt_all  = cur_all + 250000;               // 600000
    u16*   xpb   = (u16*)(srt_all + 600000);          // 100000x128 bf16
    u16*   xab   = xpb + (size_t)NPAPER * 128;        // 50000x128
    u16*   hpw   = xab + (size_t)NAUTH * 128;         // 100000x128
    u16*   haw   = hpw + (size_t)NPAPER * 128;        // 50000x128
    u16*   Mp    = haw + (size_t)NAUTH * 128;         // 100000x256 (cites|writes means)
    u16*   Ma    = Mp + (size_t)NPAPER * 256;         // 50000x128  (wb means)
    int*   partials = (int*)(Ma + (size_t)NAUTH * 128);  // 256 ints

    float* outp = (float*)d_out;                      // final output f32
    float* outa = outp + (size_t)NPAPER * 128;

    detect_dtypes<<<1, 256, 0, stream>>>(e0s, (const u32*)xp, (const u32*)Wm1,
                                         (const u32*)b1, flags);
    prep_weights<<<321, 256, 0, stream>>>(Wm1, b1, Wr1, WTp1, WTa1, biasp1, biasa1, flags);
    prep_weights<<<321, 256, 0, stream>>>(Wm2, b2, Wr2, WTp2, WTa2, biasp2, biasa2, flags);
    {
        size_t ntot = (size_t)(NPAPER + NAUTH) * 128;
        int nbc = (int)((ntot / 8 + 255) / 256);
        convert_x<<<nbc, 256, 0, stream>>>(xp, xa, xpb, xab, flags);
    }

    // ---- CSR build: 1 memset + 1 hist + 3-pass scan + 1 scatter ----
    {
        hipMemsetAsync(cnt_all, 0, (size_t)NROWS * 4, stream);
        int nb0 = (E0 + 255) / 256, nb1 = (E1 + 255) / 256, nb2 = (E2 + 255) / 256;
        hist3<<<nb0 + nb1 + nb2, 256, 0, stream>>>(e0d, e1d, e2d, E0, E1, E2,
                                                   nb0, nb1, cnt_all, flags);
        int nbs = (NROWS + 1023) / 1024;               // 245 <= 256
        scan_blksum<<<nbs, 256, 0, stream>>>(cnt_all, NROWS, partials);
        scan_partials<<<1, 256, 0, stream>>>(partials, nbs);
        scan_write<<<nbs, 256, 0, stream>>>(cnt_all, NROWS, partials, rp_all, cur_all);
        scatter3<<<nb0 + nb1 + nb2, 256, 0, stream>>>(e0s, e0d, e1s, e1d, e2s, e2d,
                                                      E0, E1, E2, nb0, nb1,
                                                      cur_all, srt_all, flags);
    }

    const int* rp_cites  = rp_all;                    // rows [0,100000]
    const int* rp_writes = rp_all + NPAPER;           // rows [0,100000]
    const int* rp_wb     = rp_all + 2 * NPAPER;       // rows [0,50000]

    for (int layer = 0; layer < 2; ++layer) {
        const u16* fp = layer ? hpw : xpb;
        const u16* fa = layer ? haw : xab;
        void* op = layer ? (void*)outp : (void*)hpw;
        void* oa = layer ? (void*)outa : (void*)haw;
        int of32 = layer ? 1 : 0;
        const u16* WTp = layer ? WTp2 : WTp1;
        const u16* WTa = layer ? WTa2 : WTa1;
        const float* bp = layer ? biasp2 : biasp1;
        const float* ba = layer ? biasa2 : biasa1;
        int relu = layer ? 0 : 1;

        // papers: means for both edge types into Mp[:,0:128] and Mp[:,128:256]
        agg_csr<<<(NPAPER * 64 + 255) / 256, 256, 0, stream>>>(
            fp, rp_cites, srt_all, NPAPER, Mp, 256, 0);
        agg_csr<<<(NPAPER * 64 + 255) / 256, 256, 0, stream>>>(
            fa, rp_writes, srt_all, NPAPER, Mp, 256, 128);
        // one fused K=384 GEMM: [mc | mw | root] @ [Wm0; Wm1; Wr0+Wr1] + (b0+b1)
        gemm_kernel<<<(NPAPER + 127) / 128, 256, 0, stream>>>(
            Mp, 256, 256, fp, WTp, bp, op, of32, 384, NPAPER, relu);

        // authors: K=256 GEMM: [m_wb | root] @ [Wm2; Wr2] + b2
        agg_csr<<<(NAUTH * 64 + 255) / 256, 256, 0, stream>>>(
            fp, rp_wb, srt_all, NAUTH, Ma, 128, 0);
        gemm_kernel<<<(NAUTH + 127) / 128, 256, 0, stream>>>(
            Ma, 128, 128, fa, WTa, ba, oa, of32, 256, NAUTH, relu);
    }
}

// Round 3
// 535.331 us; speedup vs baseline: 2.4722x; 1.1980x over previous
//
#include <hip/hip_runtime.h>

typedef unsigned short u16;
typedef unsigned int u32;
typedef __bf16 bf16x8 __attribute__((ext_vector_type(8)));
typedef float f32x4 __attribute__((ext_vector_type(4)));

#define NPAPER 100000
#define NAUTH  50000

struct alignas(16) U4 { u32 a, b, c, d; };
struct alignas(8)  U2 { u32 a, b; };
struct alignas(16) F4 { float x, y, z, w; };

__device__ __forceinline__ float bf2f(u16 u) {
    union { u32 i; float f; } v; v.i = ((u32)u) << 16; return v.f;
}
__device__ __forceinline__ u16 f2bf(float f) {
    union { float f; u32 i; } v; v.f = f;
    u32 u = v.i;
    return (u16)((u + 0x7FFFu + ((u >> 16) & 1u)) >> 16);
}

// flags: [0]=idx_is_int64 [1]=x_is_f32 [2]=W_is_f32 [3]=b_is_f32
__device__ __forceinline__ float ldf(const void* p, size_t i, int f32) {
    return f32 ? ((const float*)p)[i] : bf2f(((const u16*)p)[i]);
}

__global__ void detect_dtypes(const int* __restrict__ e, const u32* __restrict__ x,
                              const u32* __restrict__ w, const u32* __restrict__ bb,
                              int* __restrict__ flags)
{
    int t = threadIdx.x, wave = t >> 6, lane = t & 63;
    if (wave == 0) {
        int v = e[lane];
        unsigned long long m = __ballot((lane & 1) && v == 0);
        if (lane == 0) flags[0] = (__popcll(m) >= 24) ? 1 : 0;
    } else {
        const u32* p = (wave == 1) ? x : ((wave == 2) ? w : bb);
        u32 wd = p[lane];
        int ex = (int)((wd >> 7) & 0xFFu);   // exponent of low-half-as-bf16
        unsigned long long m = __ballot(ex >= 105 && ex <= 140);
        if (lane == 0) flags[wave] = (__popcll(m) >= 40) ? 0 : 1;   // 1 = f32
    }
}

// ---- upfront feature conversion: x_paper,x_author -> bf16 (copy if already bf16)
__global__ __launch_bounds__(256) void convert_x(
    const void* __restrict__ xp, const void* __restrict__ xa,
    u16* __restrict__ xpb, u16* __restrict__ xab, const int* __restrict__ flags)
{
    int f32 = flags[1];
    size_t i = ((size_t)blockIdx.x * 256 + threadIdx.x) * 8;
    const size_t np = (size_t)NPAPER * 128, ntot = np + (size_t)NAUTH * 128;
    if (i >= ntot) return;
    const void* s; u16* d; size_t off;
    if (i < np) { s = xp; d = xpb; off = i; }
    else        { s = xa; d = xab; off = i - np; }
    alignas(16) u16 o[8];
    if (f32) {
        const F4* f = (const F4*)((const float*)s + off);
        F4 f0 = f[0], f1 = f[1];
        o[0] = f2bf(f0.x); o[1] = f2bf(f0.y); o[2] = f2bf(f0.z); o[3] = f2bf(f0.w);
        o[4] = f2bf(f1.x); o[5] = f2bf(f1.y); o[6] = f2bf(f1.z); o[7] = f2bf(f1.w);
    } else {
        *(U4*)o = *(const U4*)((const u16*)s + off);
    }
    *(U4*)(d + off) = *(const U4*)o;
}

// ---- weight prep (one layer), with epilogue column permutation ----
// GEMM B-row j (0..127) holds PHYSICAL output column n(j):
//   s=j>>6, u=j&63, c=u>>4, fr=u&15  ->  n = s*64 + fr*4 + c
// so that MFMA frag (c,fr) owns 4 ADJACENT phys cols -> float4 stores.
//  WTp[j*384+k]: k<128 -> Wm0(k,n); k<256 -> Wm1(k-128,n); else (Wr0+Wr1)(k-256,n)
//  WTa[j*256+k]: k<128 -> Wm2(k,n); else Wr2(k-128,n)
//  biasp = b0+b1; biasa = b2 (NOT permuted; epilogue indexes by phys col)
__device__ __forceinline__ int permcol(int j) {
    int s = j >> 6, u = j & 63, c = u >> 4, fr = u & 15;
    return s * 64 + fr * 4 + c;
}

__global__ __launch_bounds__(256) void prep_weights(
    const void* __restrict__ Wm, const void* __restrict__ b, const void* __restrict__ Wr,
    u16* __restrict__ WTp, u16* __restrict__ WTa,
    float* __restrict__ biasp, float* __restrict__ biasa,
    const int* __restrict__ flags)
{
    int wf = flags[2], bf = flags[3];
    int tid = blockIdx.x * 256 + threadIdx.x;
    if (tid < 49152) {
        int j = tid / 384, k = tid - j * 384;
        int n = permcol(j);
        float v;
        if (k < 128)      v = ldf(Wm, k * 128 + n, wf);
        else if (k < 256) v = ldf(Wm, 16384 + (k - 128) * 128 + n, wf);
        else              v = ldf(Wr, (k - 256) * 128 + n, wf)
                            + ldf(Wr, 16384 + (k - 256) * 128 + n, wf);
        WTp[j * 384 + k] = f2bf(v);
    } else if (tid < 81920) {
        int idx = tid - 49152;
        int j = idx >> 8, k = idx & 255;
        int n = permcol(j);
        float v = (k < 128) ? ldf(Wm, 2 * 16384 + k * 128 + n, wf)
                            : ldf(Wr, 2 * 16384 + (k - 128) * 128 + n, wf);
        WTa[j * 256 + k] = f2bf(v);
    } else if (tid < 82176) {
        int i = tid - 81920;
        if (i < 128) biasp[i] = ldf(b, i, bf) + ldf(b, 128 + i, bf);
        else         biasa[i - 128] = ldf(b, 256 + (i - 128), bf);
    }
}

// ---------------- CSR build (3 edge types concatenated) ----------------
__global__ __launch_bounds__(256) void hist3(
    const int* __restrict__ e0d, const int* __restrict__ e1d, const int* __restrict__ e2d,
    int E0, int E1, int E2, int nb0, int nb1,
    int* __restrict__ cnt, const int* __restrict__ flags)
{
    int b = blockIdx.x;
    const int* dptr; int E, base, i;
    if (b < nb0)            { dptr = e0d; E = E0; base = 0;          i = b * 256 + threadIdx.x; }
    else if (b < nb0 + nb1) { dptr = e1d; E = E1; base = NPAPER;     i = (b - nb0) * 256 + threadIdx.x; }
    else                    { dptr = e2d; E = E2; base = 2 * NPAPER; i = (b - nb0 - nb1) * 256 + threadIdx.x; }
    if (i >= E) return;
    int d = dptr[flags[0] ? 2 * i : i];
    atomicAdd(&cnt[base + d], 1);
}

__global__ __launch_bounds__(256) void scan_blksum(
    const int* __restrict__ cnt, int N, int* __restrict__ partials)
{
    __shared__ int ws[4];
    int t = threadIdx.x, lane = t & 63, wave = t >> 6;
    int i0 = blockIdx.x * 1024 + t * 4;
    int s = 0;
    #pragma unroll
    for (int j = 0; j < 4; ++j) {
        int i = i0 + j;
        if (i < N) s += cnt[i];
    }
    #pragma unroll
    for (int off = 32; off; off >>= 1) s += __shfl_xor(s, off);
    if (lane == 0) ws[wave] = s;
    __syncthreads();
    if (t == 0) partials[blockIdx.x] = ws[0] + ws[1] + ws[2] + ws[3];
}

__global__ __launch_bounds__(256) void scan_partials(int* __restrict__ partials, int nb)
{
    __shared__ int bs[256];
    int t = threadIdx.x;
    bs[t] = (t < nb) ? partials[t] : 0;
    __syncthreads();
    for (int off = 1; off < 256; off <<= 1) {
        int u = (t >= off) ? bs[t - off] : 0;
        __syncthreads();
        bs[t] += u;
        __syncthreads();
    }
    if (t < nb) partials[t] = (t == 0) ? 0 : bs[t - 1];
}

__global__ __launch_bounds__(256) void scan_write(
    const int* __restrict__ cnt, int N, const int* __restrict__ partials,
    int* __restrict__ rowptr, int* __restrict__ cursor)
{
    __shared__ int ws[4];
    int t = threadIdx.x, lane = t & 63, wave = t >> 6;
    int i0 = blockIdx.x * 1024 + t * 4;
    int v[4];
    #pragma unroll
    for (int j = 0; j < 4; ++j) {
        int i = i0 + j;
        v[j] = (i < N) ? cnt[i] : 0;
    }
    int s = v[0] + v[1] + v[2] + v[3];
    int sc = s;
    #pragma unroll
    for (int off = 1; off < 64; off <<= 1) {
        int u = __shfl_up(sc, off);
        if (lane >= off) sc += u;
    }
    if (lane == 63) ws[wave] = sc;
    __syncthreads();
    int woff = 0;
    #pragma unroll
    for (int wv = 0; wv < 3; ++wv) if (wv < wave) woff += ws[wv];
    int run = partials[blockIdx.x] + woff + (sc - s);
    #pragma unroll
    for (int j = 0; j < 4; ++j) {
        int i = i0 + j;
        if (i < N) {
            rowptr[i] = run; cursor[i] = run;
            run += v[j];
            if (i == N - 1) rowptr[N] = run;
        }
    }
}

__global__ __launch_bounds__(256) void scatter3(
    const int* __restrict__ e0s, const int* __restrict__ e0d,
    const int* __restrict__ e1s, const int* __restrict__ e1d,
    const int* __restrict__ e2s, const int* __restrict__ e2d,
    int E0, int E1, int E2, int nb0, int nb1,
    int* __restrict__ cursor, int* __restrict__ srt,
    const int* __restrict__ flags)
{
    int b = blockIdx.x;
    const int* sptr; const int* dptr; int E, base, i;
    if (b < nb0)            { sptr = e0s; dptr = e0d; E = E0; base = 0;          i = b * 256 + threadIdx.x; }
    else if (b < nb0 + nb1) { sptr = e1s; dptr = e1d; E = E1; base = NPAPER;     i = (b - nb0) * 256 + threadIdx.x; }
    else                    { sptr = e2s; dptr = e2d; E = E2; base = 2 * NPAPER; i = (b - nb0 - nb1) * 256 + threadIdx.x; }
    if (i >= E) return;
    int ii = flags[0] ? 2 * i : i;
    int d = dptr[ii];
    int pos = atomicAdd(&cursor[base + d], 1);
    srt[pos] = sptr[ii];
}

// ---- CSR gather-mean: one wave per dst row, bf16 in, bf16 mean out ----
__global__ __launch_bounds__(256) void agg_csr(
    const u16* __restrict__ x, const int* __restrict__ rowptr,
    const int* __restrict__ srt, int nrows,
    u16* __restrict__ M, int mstride, int mcol)
{
    int r = (blockIdx.x * 256 + threadIdx.x) >> 6;
    int lane = threadIdx.x & 63;
    if (r >= nrows) return;
    int e0 = rowptr[r], e1 = rowptr[r + 1];
    float a0 = 0.0f, a1 = 0.0f;
    for (int e = e0; e < e1; ++e) {
        int s = srt[e];
        u32 pk = ((const u32*)(x + (size_t)s * 128))[lane];
        a0 += bf2f((u16)(pk & 0xFFFFu));
        a1 += bf2f((u16)(pk >> 16));
    }
    float rcp = 1.0f / fmaxf((float)(e1 - e0), 1.0f);
    u32 pk = (u32)f2bf(a0 * rcp) | ((u32)f2bf(a1 * rcp) << 16);
    ((u32*)(M + (size_t)r * mstride + mcol))[lane] = pk;
}

// ---- fused GEMM/bias/relu: out[nrows][128] = [M | root] @ WT^T + bias ----
// B (WT, 128 rows x K) lives fully in LDS, staged in 2 K-halves (3 barriers
// per block total).  A fragments are loaded per-lane straight from global,
// double-buffered across K-steps -> the K-loop itself is barrier-free.
// Epilogue uses the permuted column order (see prep_weights) -> float4 /
// packed-bf16x4 fully-coalesced stores.
template<int K, int KM>
__global__ __launch_bounds__(256, 3) void gemm_kernel(
    const u16* __restrict__ M, int Mstride, const u16* __restrict__ root,
    const u16* __restrict__ WT, const float* __restrict__ bias,
    void* __restrict__ out, int out_f32, int nrows, int relu)
{
    constexpr int KSTEPS = K / 32;
    constexpr int KSH    = KSTEPS / 2;     // k-steps per phase
    constexpr int KHALF  = K / 2;
    constexpr int BLD    = KHALF + 8;      // padded LDS row: +16B -> 2-way max
    constexpr int KC     = KHALF / 8;      // 16B chunks per LDS row
    constexpr int CPT    = (128 * KC) / 256;  // chunks per thread per phase

    __shared__ __align__(16) u16 Bsm[128 * BLD];

    int t = threadIdx.x;
    int wave = t >> 6, lane = t & 63;
    int wm = wave >> 1, wn = wave & 1;       // 2x2 wave grid, 64x64 per wave
    int fr = lane & 15, fq = lane >> 4;

    int grow0 = blockIdx.x * 128;

    // per-fragment A row base pointers (clamped; stores guarded)
    const u16* arow[4];
    const u16* aroot[4];
    #pragma unroll
    for (int r = 0; r < 4; ++r) {
        int row = grow0 + wm * 64 + r * 16 + fr;
        if (row >= nrows) row = nrows - 1;
        arow[r]  = M + (size_t)row * Mstride;
        aroot[r] = root + (size_t)row * 128;
    }

    f32x4 acc[4][4] = {};
    bf16x8 af[2][4];

#define LOADA(buf, gks_) do {                                              \
    int k0_ = (gks_) * 32;                                                 \
    _Pragma("unroll")                                                      \
    for (int r_ = 0; r_ < 4; ++r_) {                                       \
        const u16* p_ = (k0_ < KM) ? (arow[r_] + k0_)                      \
                                   : (aroot[r_] + (k0_ - KM));             \
        af[buf][r_] = *(const bf16x8*)(p_ + fq * 8);                       \
    }                                                                      \
} while (0)

#define STAGEB(ph_) do {                                                   \
    _Pragma("unroll")                                                      \
    for (int i_ = 0; i_ < CPT; ++i_) {                                     \
        int c_ = i_ * 256 + t;                                             \
        int col_ = c_ / KC, kc_ = c_ - col_ * KC;                          \
        U4 v_ = *(const U4*)(WT + (size_t)col_ * K + (ph_) * KHALF + kc_ * 8); \
        *(U4*)(Bsm + col_ * BLD + kc_ * 8) = v_;                           \
    }                                                                      \
} while (0)

    LOADA(0, 0);                 // prefetch first A fragments
    STAGEB(0);
    __syncthreads();

    #pragma unroll
    for (int ph = 0; ph < 2; ++ph) {
        if (ph == 1) {
            __syncthreads();     // all waves done reading half 0
            STAGEB(1);
            __syncthreads();
        }
        #pragma unroll
        for (int ksl = 0; ksl < KSH; ++ksl) {
            int gks = ph * KSH + ksl;        // constant after unroll
            int cur = gks & 1;
            if (gks + 1 < KSTEPS) LOADA((gks + 1) & 1, gks + 1);
            bf16x8 bfv[4];
            #pragma unroll
            for (int c = 0; c < 4; ++c)
                bfv[c] = *(const bf16x8*)(Bsm + (wn * 64 + c * 16 + fr) * BLD
                                          + ksl * 32 + fq * 8);
            #pragma unroll
            for (int r = 0; r < 4; ++r)
                #pragma unroll
                for (int c = 0; c < 4; ++c)
                    acc[r][c] = __builtin_amdgcn_mfma_f32_16x16x32_bf16(
                        af[cur][r], bfv[c], acc[r][c], 0, 0, 0);
        }
    }
#undef LOADA
#undef STAGEB

    // epilogue: frag (c,fr) -> phys col wn*64 + 4*fr + c (permuted WT).
    // each thread owns 4 adjacent cols -> vector stores.
    float4 b4 = *(const float4*)(bias + wn * 64 + 4 * fr);
    #pragma unroll
    for (int r = 0; r < 4; ++r) {
        #pragma unroll
        for (int g = 0; g < 4; ++g) {
            int orow = grow0 + wm * 64 + r * 16 + fq * 4 + g;
            if (orow < nrows) {
                float v0 = acc[r][0][g] + b4.x;
                float v1 = acc[r][1][g] + b4.y;
                float v2 = acc[r][2][g] + b4.z;
                float v3 = acc[r][3][g] + b4.w;
                if (relu) {
                    v0 = fmaxf(v0, 0.0f); v1 = fmaxf(v1, 0.0f);
                    v2 = fmaxf(v2, 0.0f); v3 = fmaxf(v3, 0.0f);
                }
                size_t ob = (size_t)orow * 128 + wn * 64 + 4 * fr;
                if (out_f32) {
                    float4 st = { v0, v1, v2, v3 };
                    *(float4*)((float*)out + ob) = st;
                } else {
                    U2 st;
                    st.a = (u32)f2bf(v0) | ((u32)f2bf(v1) << 16);
                    st.b = (u32)f2bf(v2) | ((u32)f2bf(v3) << 16);
                    *(U2*)((u16*)out + ob) = st;
                }
            }
        }
    }
}

extern "C" void kernel_launch(void* const* d_in, const int* in_sizes, int n_in,
                              void* d_out, int out_size, void* d_ws, size_t ws_size,
                              hipStream_t stream)
{
    const void* xp  = d_in[0];
    const void* xa  = d_in[1];
    const void* Wm1 = d_in[2];
    const void* b1  = d_in[3];
    const void* Wr1 = d_in[4];
    const void* Wm2 = d_in[5];
    const void* b2  = d_in[6];
    const void* Wr2 = d_in[7];
    const int* e0s = (const int*)d_in[8];
    const int* e0d = (const int*)d_in[9];
    const int* e1s = (const int*)d_in[10];
    const int* e1d = (const int*)d_in[11];
    const int* e2s = (const int*)d_in[12];
    const int* e2d = (const int*)d_in[13];
    int E0 = in_sizes[8], E1 = in_sizes[10], E2 = in_sizes[12];

    const int NROWS = 2 * NPAPER + NAUTH;    // 250000 concatenated CSR rows

    // ---- ws layout, ~147 MiB total ----
    char* w = (char*)d_ws;
    int*   flags  = (int*)w;                          // 5 ints
    float* biasp1 = (float*)(w + 256);
    float* biasa1 = biasp1 + 128;
    float* biasp2 = biasa1 + 128;
    float* biasa2 = biasp2 + 128;
    u16*   WTp1   = (u16*)(w + 2304);                 // 128x384
    u16*   WTa1   = WTp1 + 49152;                     // 128x256
    u16*   WTp2   = WTa1 + 32768;
    u16*   WTa2   = WTp2 + 49152;
    int*   rp_all = (int*)(WTa2 + 32768);             // 250001 (+pad)
    int*   cnt_all  = rp_all + 250004;                // 250000
    int*   cur_all  = cnt_all + 250000;               // 250000
    int*   srt_all  = cur_all + 250000;               // 600000
    u16*   xpb   = (u16*)(srt_all + 600000);          // 100000x128 bf16
    u16*   xab   = xpb + (size_t)NPAPER * 128;        // 50000x128
    u16*   hpw   = xab + (size_t)NAUTH * 128;         // 100000x128
    u16*   haw   = hpw + (size_t)NPAPER * 128;        // 50000x128
    u16*   Mp    = haw + (size_t)NAUTH * 128;         // 100000x256 (cites|writes means)
    u16*   Ma    = Mp + (size_t)NPAPER * 256;         // 50000x128  (wb means)
    int*   partials = (int*)(Ma + (size_t)NAUTH * 128);  // 256 ints

    float* outp = (float*)d_out;                      // final output f32
    float* outa = outp + (size_t)NPAPER * 128;

    detect_dtypes<<<1, 256, 0, stream>>>(e0s, (const u32*)xp, (const u32*)Wm1,
                                         (const u32*)b1, flags);
    prep_weights<<<321, 256, 0, stream>>>(Wm1, b1, Wr1, WTp1, WTa1, biasp1, biasa1, flags);
    prep_weights<<<321, 256, 0, stream>>>(Wm2, b2, Wr2, WTp2, WTa2, biasp2, biasa2, flags);
    {
        size_t ntot = (size_t)(NPAPER + NAUTH) * 128;
        int nbc = (int)((ntot / 8 + 255) / 256);
        convert_x<<<nbc, 256, 0, stream>>>(xp, xa, xpb, xab, flags);
    }

    // ---- CSR build: 1 memset + 1 hist + 3-pass scan + 1 scatter ----
    {
        hipMemsetAsync(cnt_all, 0, (size_t)NROWS * 4, stream);
        int nb0 = (E0 + 255) / 256, nb1 = (E1 + 255) / 256, nb2 = (E2 + 255) / 256;
        hist3<<<nb0 + nb1 + nb2, 256, 0, stream>>>(e0d, e1d, e2d, E0, E1, E2,
                                                   nb0, nb1, cnt_all, flags);
        int nbs = (NROWS + 1023) / 1024;               // 245 <= 256
        scan_blksum<<<nbs, 256, 0, stream>>>(cnt_all, NROWS, partials);
        scan_partials<<<1, 256, 0, stream>>>(partials, nbs);
        scan_write<<<nbs, 256, 0, stream>>>(cnt_all, NROWS, partials, rp_all, cur_all);
        scatter3<<<nb0 + nb1 + nb2, 256, 0, stream>>>(e0s, e0d, e1s, e1d, e2s, e2d,
                                                      E0, E1, E2, nb0, nb1,
                                                      cur_all, srt_all, flags);
    }

    const int* rp_cites  = rp_all;                    // rows [0,100000]
    const int* rp_writes = rp_all + NPAPER;           // rows [0,100000]
    const int* rp_wb     = rp_all + 2 * NPAPER;       // rows [0,50000]

    for (int layer = 0; layer < 2; ++layer) {
        const u16* fp = layer ? hpw : xpb;
        const u16* fa = layer ? haw : xab;
        void* op = layer ? (void*)outp : (void*)hpw;
        void* oa = layer ? (void*)outa : (void*)haw;
        int of32 = layer ? 1 : 0;
        const u16* WTp = layer ? WTp2 : WTp1;
        const u16* WTa = layer ? WTa2 : WTa1;
        const float* bp = layer ? biasp2 : biasp1;
        const float* ba = layer ? biasa2 : biasa1;
        int relu = layer ? 0 : 1;

        // papers: means for both edge types into Mp[:,0:128] and Mp[:,128:256]
        agg_csr<<<(NPAPER * 64 + 255) / 256, 256, 0, stream>>>(
            fp, rp_cites, srt_all, NPAPER, Mp, 256, 0);
        agg_csr<<<(NPAPER * 64 + 255) / 256, 256, 0, stream>>>(
            fa, rp_writes, srt_all, NPAPER, Mp, 256, 128);
        // one fused K=384 GEMM: [mc | mw | root] @ [Wm0; Wm1; Wr0+Wr1] + (b0+b1)
        gemm_kernel<384, 256><<<(NPAPER + 127) / 128, 256, 0, stream>>>(
            Mp, 256, fp, WTp, bp, op, of32, NPAPER, relu);

        // authors: K=256 GEMM: [m_wb | root] @ [Wm2; Wr2] + b2
        agg_csr<<<(NAUTH * 64 + 255) / 256, 256, 0, stream>>>(
            fp, rp_wb, srt_all, NAUTH, Ma, 128, 0);
        gemm_kernel<256, 128><<<(NAUTH + 127) / 128, 256, 0, stream>>>(
            Ma, 128, fa, WTa, ba, oa, of32, NAUTH, relu);
    }
}

// Round 5
// 444.612 us; speedup vs baseline: 2.9766x; 1.2040x over previous
//
#include <hip/hip_runtime.h>

typedef unsigned short u16;
typedef unsigned int u32;
typedef __bf16 bf16x8 __attribute__((ext_vector_type(8)));
typedef float f32x4 __attribute__((ext_vector_type(4)));

#define NPAPER 100000
#define NAUTH  50000
#define NROWS_ALL (2 * NPAPER + NAUTH)

struct alignas(16) U4 { u32 a, b, c, d; };
struct alignas(8)  U2 { u32 a, b; };
struct alignas(16) F4 { float x, y, z, w; };

__device__ __forceinline__ float bf2f(u16 u) {
    union { u32 i; float f; } v; v.i = ((u32)u) << 16; return v.f;
}
__device__ __forceinline__ u16 f2bf(float f) {
    union { float f; u32 i; } v; v.f = f;
    u32 u = v.i;
    return (u16)((u + 0x7FFFu + ((u >> 16) & 1u)) >> 16);
}

// flags: [0]=idx_is_int64 [1]=x_is_f32 [2]=W_is_f32 [3]=b_is_f32
__device__ __forceinline__ float ldf(const void* p, size_t i, int f32) {
    return f32 ? ((const float*)p)[i] : bf2f(((const u16*)p)[i]);
}

__global__ void detect_dtypes(const int* __restrict__ e, const u32* __restrict__ x,
                              const u32* __restrict__ w, const u32* __restrict__ bb,
                              int* __restrict__ flags)
{
    int t = threadIdx.x, wave = t >> 6, lane = t & 63;
    if (wave == 0) {
        int v = e[lane];
        unsigned long long m = __ballot((lane & 1) && v == 0);
        if (lane == 0) flags[0] = (__popcll(m) >= 24) ? 1 : 0;
    } else {
        const u32* p = (wave == 1) ? x : ((wave == 2) ? w : bb);
        u32 wd = p[lane];
        int ex = (int)((wd >> 7) & 0xFFu);   // exponent of low-half-as-bf16
        unsigned long long m = __ballot(ex >= 105 && ex <= 140);
        if (lane == 0) flags[wave] = (__popcll(m) >= 40) ? 0 : 1;   // 1 = f32
    }
}

// ---- upfront feature conversion: x_paper,x_author -> bf16 (copy if already bf16)
__global__ __launch_bounds__(256) void convert_x(
    const void* __restrict__ xp, const void* __restrict__ xa,
    u16* __restrict__ xpb, u16* __restrict__ xab, const int* __restrict__ flags)
{
    int f32 = flags[1];
    size_t i = ((size_t)blockIdx.x * 256 + threadIdx.x) * 8;
    const size_t np = (size_t)NPAPER * 128, ntot = np + (size_t)NAUTH * 128;
    if (i >= ntot) return;
    const void* s; u16* d; size_t off;
    if (i < np) { s = xp; d = xpb; off = i; }
    else        { s = xa; d = xab; off = i - np; }
    alignas(16) u16 o[8];
    if (f32) {
        const F4* f = (const F4*)((const float*)s + off);
        F4 f0 = f[0], f1 = f[1];
        o[0] = f2bf(f0.x); o[1] = f2bf(f0.y); o[2] = f2bf(f0.z); o[3] = f2bf(f0.w);
        o[4] = f2bf(f1.x); o[5] = f2bf(f1.y); o[6] = f2bf(f1.z); o[7] = f2bf(f1.w);
    } else {
        *(U4*)o = *(const U4*)((const u16*)s + off);
    }
    *(U4*)(d + off) = *(const U4*)o;
}

// ---- weight prep (both layers, one launch), epilogue column permutation ----
// GEMM B-row j (0..127) holds PHYSICAL output column n(j):
//   s=j>>6, u=j&63, c=u>>4, fr=u&15  ->  n = s*64 + fr*4 + c
__device__ __forceinline__ int permcol(int j) {
    int s = j >> 6, u = j & 63, c = u >> 4, fr = u & 15;
    return s * 64 + fr * 4 + c;
}

__global__ __launch_bounds__(256) void prep_weights2(
    const void* __restrict__ Wm1, const void* __restrict__ b1, const void* __restrict__ Wr1,
    const void* __restrict__ Wm2, const void* __restrict__ b2, const void* __restrict__ Wr2,
    u16* __restrict__ WTp1, u16* __restrict__ WTa1,
    float* __restrict__ biasp1, float* __restrict__ biasa1,
    u16* __restrict__ WTp2, u16* __restrict__ WTa2,
    float* __restrict__ biasp2, float* __restrict__ biasa2,
    const int* __restrict__ flags)
{
    int half = blockIdx.x >= 321;
    const void* Wm = half ? Wm2 : Wm1;
    const void* b  = half ? b2  : b1;
    const void* Wr = half ? Wr2 : Wr1;
    u16* WTp = half ? WTp2 : WTp1;
    u16* WTa = half ? WTa2 : WTa1;
    float* biasp = half ? biasp2 : biasp1;
    float* biasa = half ? biasa2 : biasa1;

    int wf = flags[2], bf = flags[3];
    int tid = (blockIdx.x - half * 321) * 256 + threadIdx.x;
    if (tid < 49152) {
        int j = tid / 384, k = tid - j * 384;
        int n = permcol(j);
        float v;
        if (k < 128)      v = ldf(Wm, k * 128 + n, wf);
        else if (k < 256) v = ldf(Wm, 16384 + (k - 128) * 128 + n, wf);
        else              v = ldf(Wr, (k - 256) * 128 + n, wf)
                            + ldf(Wr, 16384 + (k - 256) * 128 + n, wf);
        WTp[j * 384 + k] = f2bf(v);
    } else if (tid < 81920) {
        int idx = tid - 49152;
        int j = idx >> 8, k = idx & 255;
        int n = permcol(j);
        float v = (k < 128) ? ldf(Wm, 2 * 16384 + k * 128 + n, wf)
                            : ldf(Wr, 2 * 16384 + (k - 128) * 128 + n, wf);
        WTa[j * 256 + k] = f2bf(v);
    } else if (tid < 82176) {
        int i = tid - 81920;
        if (i < 128) biasp[i] = ldf(b, i, bf) + ldf(b, 128 + i, bf);
        else         biasa[i - 128] = ldf(b, 256 + (i - 128), bf);
    }
}

// ---------------- CSR build (3 edge types concatenated) ----------------
__global__ __launch_bounds__(256) void hist3(
    const int* __restrict__ e0d, const int* __restrict__ e1d, const int* __restrict__ e2d,
    int E0, int E1, int E2, int nb0, int nb1,
    int* __restrict__ cnt, const int* __restrict__ flags)
{
    int b = blockIdx.x;
    const int* dptr; int E, base, i;
    if (b < nb0)            { dptr = e0d; E = E0; base = 0;          i = b * 256 + threadIdx.x; }
    else if (b < nb0 + nb1) { dptr = e1d; E = E1; base = NPAPER;     i = (b - nb0) * 256 + threadIdx.x; }
    else                    { dptr = e2d; E = E2; base = 2 * NPAPER; i = (b - nb0 - nb1) * 256 + threadIdx.x; }
    if (i >= E) return;
    int d = dptr[flags[0] ? 2 * i : i];
    atomicAdd(&cnt[base + d], 1);
}

__global__ __launch_bounds__(256) void scan_blksum(
    const int* __restrict__ cnt, int N, int* __restrict__ partials)
{
    __shared__ int ws[4];
    int t = threadIdx.x, lane = t & 63, wave = t >> 6;
    int i0 = blockIdx.x * 1024 + t * 4;
    int s = 0;
    #pragma unroll
    for (int j = 0; j < 4; ++j) {
        int i = i0 + j;
        if (i < N) s += cnt[i];
    }
    #pragma unroll
    for (int off = 32; off; off >>= 1) s += __shfl_xor(s, off);
    if (lane == 0) ws[wave] = s;
    __syncthreads();
    if (t == 0) partials[blockIdx.x] = ws[0] + ws[1] + ws[2] + ws[3];
}

__global__ __launch_bounds__(256) void scan_partials(int* __restrict__ partials, int nb)
{
    __shared__ int bs[256];
    int t = threadIdx.x;
    bs[t] = (t < nb) ? partials[t] : 0;
    __syncthreads();
    for (int off = 1; off < 256; off <<= 1) {
        int u = (t >= off) ? bs[t - off] : 0;
        __syncthreads();
        bs[t] += u;
        __syncthreads();
    }
    if (t < nb) partials[t] = (t == 0) ? 0 : bs[t - 1];
}

__global__ __launch_bounds__(256) void scan_write(
    const int* __restrict__ cnt, int N, const int* __restrict__ partials,
    int* __restrict__ rowptr, int* __restrict__ cursor)
{
    __shared__ int ws[4];
    int t = threadIdx.x, lane = t & 63, wave = t >> 6;
    int i0 = blockIdx.x * 1024 + t * 4;
    int v[4];
    #pragma unroll
    for (int j = 0; j < 4; ++j) {
        int i = i0 + j;
        v[j] = (i < N) ? cnt[i] : 0;
    }
    int s = v[0] + v[1] + v[2] + v[3];
    int sc = s;
    #pragma unroll
    for (int off = 1; off < 64; off <<= 1) {
        int u = __shfl_up(sc, off);
        if (lane >= off) sc += u;
    }
    if (lane == 63) ws[wave] = sc;
    __syncthreads();
    int woff = 0;
    #pragma unroll
    for (int wv = 0; wv < 3; ++wv) if (wv < wave) woff += ws[wv];
    int run = partials[blockIdx.x] + woff + (sc - s);
    #pragma unroll
    for (int j = 0; j < 4; ++j) {
        int i = i0 + j;
        if (i < N) {
            rowptr[i] = run; cursor[i] = run;
            run += v[j];
            if (i == N - 1) rowptr[N] = run;
        }
    }
}

__global__ __launch_bounds__(256) void scatter3(
    const int* __restrict__ e0s, const int* __restrict__ e0d,
    const int* __restrict__ e1s, const int* __restrict__ e1d,
    const int* __restrict__ e2s, const int* __restrict__ e2d,
    int E0, int E1, int E2, int nb0, int nb1,
    int* __restrict__ cursor, int* __restrict__ srt,
    const int* __restrict__ flags)
{
    int b = blockIdx.x;
    const int* sptr; const int* dptr; int E, base, i;
    if (b < nb0)            { sptr = e0s; dptr = e0d; E = E0; base = 0;          i = b * 256 + threadIdx.x; }
    else if (b < nb0 + nb1) { sptr = e1s; dptr = e1d; E = E1; base = NPAPER;     i = (b - nb0) * 256 + threadIdx.x; }
    else                    { sptr = e2s; dptr = e2d; E = E2; base = 2 * NPAPER; i = (b - nb0 - nb1) * 256 + threadIdx.x; }
    if (i >= E) return;
    int ii = flags[0] ? 2 * i : i;
    int d = dptr[ii];
    int pos = atomicAdd(&cursor[base + d], 1);
    srt[pos] = sptr[ii];
}

// ---- unified CSR gather-mean over all 250K concatenated rows ----
// rows [0,NPAPER): cites (src=xp) -> Mp[:,0:128)
// rows [NPAPER,2*NPAPER): writes (src=xa) -> Mp[:,128:256)
// rows [2*NPAPER,250K): writes-back (src=xp) -> Ma[:,0:128)
// Predicated batch-of-4 gather: 4 independent loads in flight per step.
__global__ __launch_bounds__(256) void agg_all(
    const u16* __restrict__ xp, const u16* __restrict__ xa,
    const int* __restrict__ rp_all, const int* __restrict__ srt,
    u16* __restrict__ Mp, u16* __restrict__ Ma)
{
    int r = (blockIdx.x * 256 + threadIdx.x) >> 6;
    int lane = threadIdx.x & 63;
    if (r >= NROWS_ALL) return;

    const u16* x; u32* dst;
    if (r < NPAPER)            { x = xp; dst = (u32*)(Mp + (size_t)r * 256); }
    else if (r < 2 * NPAPER)   { x = xa; dst = (u32*)(Mp + (size_t)(r - NPAPER) * 256 + 128); }
    else                       { x = xp; dst = (u32*)(Ma + (size_t)(r - 2 * NPAPER) * 128); }

    int e0 = rp_all[r], e1 = rp_all[r + 1];
    float a0 = 0.0f, a1 = 0.0f;
    for (int e = e0; e < e1; e += 4) {
        int el = e1 - 1;
        int i1 = e + 1 < e1 ? e + 1 : el;
        int i2 = e + 2 < e1 ? e + 2 : el;
        int i3 = e + 3 < e1 ? e + 3 : el;
        int s0 = srt[e], s1 = srt[i1], s2 = srt[i2], s3 = srt[i3];
        u32 p0 = ((const u32*)(x + (size_t)s0 * 128))[lane];
        u32 p1 = ((const u32*)(x + (size_t)s1 * 128))[lane];
        u32 p2 = ((const u32*)(x + (size_t)s2 * 128))[lane];
        u32 p3 = ((const u32*)(x + (size_t)s3 * 128))[lane];
        p1 = (e + 1 < e1) ? p1 : 0u;
        p2 = (e + 2 < e1) ? p2 : 0u;
        p3 = (e + 3 < e1) ? p3 : 0u;
        a0 += bf2f((u16)(p0 & 0xFFFFu)) + bf2f((u16)(p1 & 0xFFFFu))
            + bf2f((u16)(p2 & 0xFFFFu)) + bf2f((u16)(p3 & 0xFFFFu));
        a1 += bf2f((u16)(p0 >> 16)) + bf2f((u16)(p1 >> 16))
            + bf2f((u16)(p2 >> 16)) + bf2f((u16)(p3 >> 16));
    }
    float rcp = 1.0f / fmaxf((float)(e1 - e0), 1.0f);
    dst[lane] = (u32)f2bf(a0 * rcp) | ((u32)f2bf(a1 * rcp) << 16);
}

// ---- fused GEMM/bias/relu body: out[nrows][128] = [M | root] @ WT^T + bias ----
// B (WT) staged fully into LDS in 2 K-halves (3 barriers/block); A fragments
// loaded per-lane from global, double-buffered -> barrier-free K-loop.
// Epilogue uses permuted column order -> float4 / packed-bf16x4 stores.
template<int K, int KM>
__device__ __forceinline__ void gemm_body(
    u16* __restrict__ Bsm, int bx,
    const u16* __restrict__ M, int Mstride, const u16* __restrict__ root,
    const u16* __restrict__ WT, const float* __restrict__ bias,
    void* __restrict__ out, int out_f32, int nrows, int relu)
{
    constexpr int KSTEPS = K / 32;
    constexpr int KSH    = KSTEPS / 2;
    constexpr int KHALF  = K / 2;
    constexpr int BLD    = KHALF + 8;      // padded LDS row -> 2-way max (free)
    constexpr int KC     = KHALF / 8;
    constexpr int CPT    = (128 * KC) / 256;

    int t = threadIdx.x;
    int wave = t >> 6, lane = t & 63;
    int wm = wave >> 1, wn = wave & 1;
    int fr = lane & 15, fq = lane >> 4;

    int grow0 = bx * 128;

    const u16* arow[4];
    const u16* aroot[4];
    #pragma unroll
    for (int r = 0; r < 4; ++r) {
        int row = grow0 + wm * 64 + r * 16 + fr;
        if (row >= nrows) row = nrows - 1;
        arow[r]  = M + (size_t)row * Mstride;
        aroot[r] = root + (size_t)row * 128;
    }

    f32x4 acc[4][4] = {};
    bf16x8 af[2][4];

#define LOADA(buf, gks_) do {                                              \
    int k0_ = (gks_) * 32;                                                 \
    _Pragma("unroll")                                                      \
    for (int r_ = 0; r_ < 4; ++r_) {                                       \
        const u16* p_ = (k0_ < KM) ? (arow[r_] + k0_)                      \
                                   : (aroot[r_] + (k0_ - KM));             \
        af[buf][r_] = *(const bf16x8*)(p_ + fq * 8);                       \
    }                                                                      \
} while (0)

#define STAGEB(ph_) do {                                                   \
    _Pragma("unroll")                                                      \
    for (int i_ = 0; i_ < CPT; ++i_) {                                     \
        int c_ = i_ * 256 + t;                                             \
        int col_ = c_ / KC, kc_ = c_ - col_ * KC;                          \
        U4 v_ = *(const U4*)(WT + (size_t)col_ * K + (ph_) * KHALF + kc_ * 8); \
        *(U4*)(Bsm + col_ * BLD + kc_ * 8) = v_;                           \
    }                                                                      \
} while (0)

    LOADA(0, 0);
    STAGEB(0);
    __syncthreads();

    #pragma unroll
    for (int ph = 0; ph < 2; ++ph) {
        if (ph == 1) {
            __syncthreads();
            STAGEB(1);
            __syncthreads();
        }
        #pragma unroll
        for (int ksl = 0; ksl < KSH; ++ksl) {
            int gks = ph * KSH + ksl;
            int cur = gks & 1;
            if (gks + 1 < KSTEPS) LOADA((gks + 1) & 1, gks + 1);
            bf16x8 bfv[4];
            #pragma unroll
            for (int c = 0; c < 4; ++c)
                bfv[c] = *(const bf16x8*)(Bsm + (wn * 64 + c * 16 + fr) * BLD
                                          + ksl * 32 + fq * 8);
            #pragma unroll
            for (int r = 0; r < 4; ++r)
                #pragma unroll
                for (int c = 0; c < 4; ++c)
                    acc[r][c] = __builtin_amdgcn_mfma_f32_16x16x32_bf16(
                        af[cur][r], bfv[c], acc[r][c], 0, 0, 0);
        }
    }
#undef LOADA
#undef STAGEB

    float4 b4 = *(const float4*)(bias + wn * 64 + 4 * fr);
    #pragma unroll
    for (int r = 0; r < 4; ++r) {
        #pragma unroll
        for (int g = 0; g < 4; ++g) {
            int orow = grow0 + wm * 64 + r * 16 + fq * 4 + g;
            if (orow < nrows) {
                float v0 = acc[r][0][g] + b4.x;
                float v1 = acc[r][1][g] + b4.y;
                float v2 = acc[r][2][g] + b4.z;
                float v3 = acc[r][3][g] + b4.w;
                if (relu) {
                    v0 = fmaxf(v0, 0.0f); v1 = fmaxf(v1, 0.0f);
                    v2 = fmaxf(v2, 0.0f); v3 = fmaxf(v3, 0.0f);
                }
                size_t ob = (size_t)orow * 128 + wn * 64 + 4 * fr;
                if (out_f32) {
                    float4 st = { v0, v1, v2, v3 };
                    *(float4*)((float*)out + ob) = st;
                } else {
                    U2 st;
                    st.a = (u32)f2bf(v0) | ((u32)f2bf(v1) << 16);
                    st.b = (u32)f2bf(v2) | ((u32)f2bf(v3) << 16);
                    *(U2*)((u16*)out + ob) = st;
                }
            }
        }
    }
}

// one launch per layer: paper blocks (K=384) then author blocks (K=256)
__global__ __launch_bounds__(256, 3) void gemm_dual(
    const u16* __restrict__ Mp, const u16* __restrict__ fp,
    const u16* __restrict__ WTp, const float* __restrict__ bp, void* __restrict__ op,
    const u16* __restrict__ Ma, const u16* __restrict__ fa,
    const u16* __restrict__ WTa, const float* __restrict__ ba, void* __restrict__ oa,
    int out_f32, int relu, int nbp)
{
    __shared__ __align__(16) u16 Bsm[128 * 200];   // max BLD = 192+8
    if ((int)blockIdx.x < nbp)
        gemm_body<384, 256>(Bsm, blockIdx.x, Mp, 256, fp, WTp, bp, op, out_f32, NPAPER, relu);
    else
        gemm_body<256, 128>(Bsm, blockIdx.x - nbp, Ma, 128, fa, WTa, ba, oa, out_f32, NAUTH, relu);
}

extern "C" void kernel_launch(void* const* d_in, const int* in_sizes, int n_in,
                              void* d_out, int out_size, void* d_ws, size_t ws_size,
                              hipStream_t stream)
{
    const void* xp  = d_in[0];
    const void* xa  = d_in[1];
    const void* Wm1 = d_in[2];
    const void* b1  = d_in[3];
    const void* Wr1 = d_in[4];
    const void* Wm2 = d_in[5];
    const void* b2  = d_in[6];
    const void* Wr2 = d_in[7];
    const int* e0s = (const int*)d_in[8];
    const int* e0d = (const int*)d_in[9];
    const int* e1s = (const int*)d_in[10];
    const int* e1d = (const int*)d_in[11];
    const int* e2s = (const int*)d_in[12];
    const int* e2d = (const int*)d_in[13];
    int E0 = in_sizes[8], E1 = in_sizes[10], E2 = in_sizes[12];

    // ---- ws layout, ~147 MiB total ----
    char* w = (char*)d_ws;
    int*   flags  = (int*)w;                          // 5 ints
    float* biasp1 = (float*)(w + 256);
    float* biasa1 = biasp1 + 128;
    float* biasp2 = biasa1 + 128;
    float* biasa2 = biasp2 + 128;
    u16*   WTp1   = (u16*)(w + 2304);                 // 128x384
    u16*   WTa1   = WTp1 + 49152;                     // 128x256
    u16*   WTp2   = WTa1 + 32768;
    u16*   WTa2   = WTp2 + 49152;
    int*   rp_all = (int*)(WTa2 + 32768);             // 250001 (+pad)
    int*   cnt_all  = rp_all + 250004;                // 250000
    int*   cur_all  = cnt_all + 250000;               // 250000
    int*   srt_all  = cur_all + 250000;               // 600000
    u16*   xpb   = (u16*)(srt_all + 600000);          // 100000x128 bf16
    u16*   xab   = xpb + (size_t)NPAPER * 128;        // 50000x128
    u16*   hpw   = xab + (size_t)NAUTH * 128;         // 100000x128
    u16*   haw   = hpw + (size_t)NPAPER * 128;        // 50000x128
    u16*   Mp    = haw + (size_t)NAUTH * 128;         // 100000x256 (cites|writes means)
    u16*   Ma    = Mp + (size_t)NPAPER * 256;         // 50000x128  (wb means)
    int*   partials = (int*)(Ma + (size_t)NAUTH * 128);  // 256 ints

    float* outp = (float*)d_out;                      // final output f32
    float* outa = outp + (size_t)NPAPER * 128;

    detect_dtypes<<<1, 256, 0, stream>>>(e0s, (const u32*)xp, (const u32*)Wm1,
                                         (const u32*)b1, flags);
    prep_weights2<<<642, 256, 0, stream>>>(Wm1, b1, Wr1, Wm2, b2, Wr2,
                                           WTp1, WTa1, biasp1, biasa1,
                                           WTp2, WTa2, biasp2, biasa2, flags);
    {
        size_t ntot = (size_t)(NPAPER + NAUTH) * 128;
        int nbc = (int)((ntot / 8 + 255) / 256);
        convert_x<<<nbc, 256, 0, stream>>>(xp, xa, xpb, xab, flags);
    }

    // ---- CSR build: 1 memset + 1 hist + 3-pass scan + 1 scatter ----
    {
        hipMemsetAsync(cnt_all, 0, (size_t)NROWS_ALL * 4, stream);
        int nb0 = (E0 + 255) / 256, nb1 = (E1 + 255) / 256, nb2 = (E2 + 255) / 256;
        hist3<<<nb0 + nb1 + nb2, 256, 0, stream>>>(e0d, e1d, e2d, E0, E1, E2,
                                                   nb0, nb1, cnt_all, flags);
        int nbs = (NROWS_ALL + 1023) / 1024;           // 245 <= 256
        scan_blksum<<<nbs, 256, 0, stream>>>(cnt_all, NROWS_ALL, partials);
        scan_partials<<<1, 256, 0, stream>>>(partials, nbs);
        scan_write<<<nbs, 256, 0, stream>>>(cnt_all, NROWS_ALL, partials, rp_all, cur_all);
        scatter3<<<nb0 + nb1 + nb2, 256, 0, stream>>>(e0s, e0d, e1s, e1d, e2s, e2d,
                                                      E0, E1, E2, nb0, nb1,
                                                      cur_all, srt_all, flags);
    }

    const int NBP = (NPAPER + 127) / 128;             // 782 paper blocks
    const int NBA = (NAUTH + 127) / 128;              // 391 author blocks

    for (int layer = 0; layer < 2; ++layer) {
        const u16* fp = layer ? hpw : xpb;
        const u16* fa = layer ? haw : xab;
        void* op = layer ? (void*)outp : (void*)hpw;
        void* oa = layer ? (void*)outa : (void*)haw;
        int of32 = layer ? 1 : 0;
        const u16* WTp = layer ? WTp2 : WTp1;
        const u16* WTa = layer ? WTa2 : WTa1;
        const float* bp = layer ? biasp2 : biasp1;
        const float* ba = layer ? biasa2 : biasa1;
        int relu = layer ? 0 : 1;

        // all 3 aggregations in one launch (250K rows)
        agg_all<<<(NROWS_ALL * 64 + 255) / 256, 256, 0, stream>>>(
            fp, fa, rp_all, srt_all, Mp, Ma);

        // both GEMMs in one launch
        gemm_dual<<<NBP + NBA, 256, 0, stream>>>(
            Mp, fp, WTp, bp, op, Ma, fa, WTa, ba, oa, of32, relu, NBP);
    }
}